// Round 7
// baseline (495.885 us; speedup 1.0000x reference)
//
#include <hip/hip_runtime.h>
#include <hip/hip_bf16.h>

// HAN forward, del-branch only (add-branch _group output is unused in the reference).
// Inputs f32 / int32; output f32 [4096,256]. h stored bf16.
//
// R7 change: gemm restructured to barrier-free persistent-B (R5/kgemm pattern).
// 256 blocks = 1/CU: stage 64 W-cols as bf16 in LDS once (103 KB), then each wave
// loops 32-row m-tiles with NO syncthreads: A double-buffered in 4-kstep register
// batches (16 indep dwordx4 in flight under 32 MFMAs). X re-read 4x via L3;
// XCD-swizzle co-locates the 4 col-group siblings for L2 line sharing.

typedef unsigned short u16;
typedef __attribute__((ext_vector_type(8))) __bf16 bf16x8;
typedef __attribute__((ext_vector_type(4))) float f32x4;

__device__ inline float bf2f(u16 u) {
    union { unsigned int i; float f; } c; c.i = ((unsigned int)u) << 16; return c.f;
}
__device__ inline u16 f2bf(float f) {  // round-to-nearest-even
    union { float f; unsigned int i; } c; c.f = f;
    return (u16)((c.i + 0x7fffu + ((c.i >> 16) & 1u)) >> 16);
}
__device__ inline bf16x8 cvt8(f32x4 a, f32x4 b) {
    bf16x8 r;
    r[0] = (__bf16)a[0]; r[1] = (__bf16)a[1]; r[2] = (__bf16)a[2]; r[3] = (__bf16)a[3];
    r[4] = (__bf16)b[0]; r[5] = (__bf16)b[1]; r[6] = (__bf16)b[2]; r[7] = (__bf16)b[3];
    return r;
}
__device__ inline float fast_tanh(float x) {
    x = fminf(9.f, fmaxf(-9.f, x));
    float t = __expf(2.f * x);
    return (t - 1.f) / (t + 1.f);
}

// ---------------- 1. h = X @ W^T + b : barrier-free persistent-B --------------------
// 256 blocks: id -> (xcd, p, bn); p -> (wh, mg). Block stages W[bn*64..+64)[768] bf16
// into LDS (stride PB=808 u16), then 4 waves independently process m-tiles
// mt = mg + 32*(w + 4i)  (20000 rows = 625 32-row tiles; no bounds checks needed).
#define PB 808
__global__ __launch_bounds__(256, 1) void gemm_persist(
    const float* __restrict__ X0, const float* __restrict__ W0,
    const float* __restrict__ b0, u16* __restrict__ H0,
    const float* __restrict__ X1, const float* __restrict__ W1,
    const float* __restrict__ b1, u16* __restrict__ H1) {
    __shared__ u16 Bs[64 * PB];          // 103.4 KB
    int id = blockIdx.x;
    int xcd = id & 7, j = id >> 3;
    int bn = j & 3;                      // 64-col group of W
    int p = xcd * 8 + (j >> 2);          // 0..63: same-p siblings share X rows
    int wh = p & 1, mg = p >> 1;         // matrix select, m-group 0..31
    const float* X = wh ? X1 : X0;
    const float* W = wh ? W1 : W0;
    const float* bias = wh ? b1 : b0;
    u16* H = wh ? H1 : H0;
    int tid = threadIdx.x, w = tid >> 6, lane = tid & 63;
    int row16 = lane & 15, quad = lane >> 4;

    // stage W slice -> bf16 LDS (once per block)
    {
        const float* wsrc = W + (size_t)bn * 64 * 768;
        for (int c = tid; c < 6144; c += 256) {
            int r = c / 96, col8 = (c - r * 96) * 8;
            const float* s = wsrc + (size_t)r * 768 + col8;
            *(bf16x8*)(Bs + r * PB + col8) = cvt8(*(const f32x4*)s, *(const f32x4*)(s + 4));
        }
    }
    __syncthreads();                     // the ONLY barrier

    float bv[4];
#pragma unroll
    for (int ni = 0; ni < 4; ++ni) bv[ni] = bias[bn * 64 + ni * 16 + row16];
    const u16* bfr = Bs + row16 * PB + quad * 8;

    for (int t = w; mg + 32 * t < 625; t += 4) {
        int mt = mg + 32 * t;
        const float* a0p = X + (size_t)(mt * 32 + row16) * 768 + quad * 8;
        const float* a1p = a0p + 16 * 768;
        f32x4 A[2][16];
#pragma unroll
        for (int ks = 0; ks < 4; ++ks) {  // group 0 loads
            A[0][ks * 4 + 0] = *(const f32x4*)(a0p + ks * 32);
            A[0][ks * 4 + 1] = *(const f32x4*)(a0p + ks * 32 + 4);
            A[0][ks * 4 + 2] = *(const f32x4*)(a1p + ks * 32);
            A[0][ks * 4 + 3] = *(const f32x4*)(a1p + ks * 32 + 4);
        }
        f32x4 acc[2][4] = {};
#pragma unroll
        for (int g = 0; g < 6; ++g) {     // 6 groups x 4 ksteps x 32k = K=768
            int cur = g & 1;
            if (g < 5) {                  // prefetch next group
                int kb = (g + 1) * 128;
#pragma unroll
                for (int ks = 0; ks < 4; ++ks) {
                    A[cur ^ 1][ks * 4 + 0] = *(const f32x4*)(a0p + kb + ks * 32);
                    A[cur ^ 1][ks * 4 + 1] = *(const f32x4*)(a0p + kb + ks * 32 + 4);
                    A[cur ^ 1][ks * 4 + 2] = *(const f32x4*)(a1p + kb + ks * 32);
                    A[cur ^ 1][ks * 4 + 3] = *(const f32x4*)(a1p + kb + ks * 32 + 4);
                }
            }
#pragma unroll
            for (int ks = 0; ks < 4; ++ks) {
                bf16x8 af0 = cvt8(A[cur][ks * 4 + 0], A[cur][ks * 4 + 1]);
                bf16x8 af1 = cvt8(A[cur][ks * 4 + 2], A[cur][ks * 4 + 3]);
                const u16* bk = bfr + g * 128 + ks * 32;
#pragma unroll
                for (int ni = 0; ni < 4; ++ni) {
                    bf16x8 bb = *(const bf16x8*)(bk + ni * 16 * PB);
                    acc[0][ni] = __builtin_amdgcn_mfma_f32_16x16x32_bf16(af0, bb, acc[0][ni], 0, 0, 0);
                    acc[1][ni] = __builtin_amdgcn_mfma_f32_16x16x32_bf16(af1, bb, acc[1][ni], 0, 0, 0);
                }
            }
        }
#pragma unroll
        for (int ni = 0; ni < 4; ++ni) {
            int gcol = bn * 64 + ni * 16 + row16;
#pragma unroll
            for (int mi = 0; mi < 2; ++mi) {
#pragma unroll
                for (int r = 0; r < 4; ++r) {
                    H[(size_t)(mt * 32 + mi * 16 + quad * 4 + r) * 256 + gcol] =
                        f2bf(acc[mi][ni][r] + bv[ni]);
                }
            }
        }
    }
}

// ---------------- 2. per-(node,head) attention scores (h bf16) ----------------------
__global__ __launch_bounds__(256) void node_scores(const u16* __restrict__ ha, const u16* __restrict__ hd,
                                                   const float* __restrict__ w_ads, const float* __restrict__ w_add,
                                                   const float* __restrict__ w_dds, const float* __restrict__ w_ddd,
                                                   float* __restrict__ as_ad, float* __restrict__ ad_ad,
                                                   float* __restrict__ as_dd, float* __restrict__ ad_dd, int N) {
    int gid = blockIdx.x * 256 + threadIdx.x;
    int n = gid >> 6;
    if (n >= N) return;
    int lane = gid & 63;
    int f = lane * 4;
    ushort4 av = *(const ushort4*)(ha + (size_t)n * 256 + f);
    ushort4 dv = *(const ushort4*)(hd + (size_t)n * 256 + f);
    float4 w1 = *(const float4*)(w_ads + f);
    float4 w2 = *(const float4*)(w_add + f);
    float4 w3 = *(const float4*)(w_dds + f);
    float4 w4 = *(const float4*)(w_ddd + f);
    float a0 = bf2f(av.x), a1 = bf2f(av.y), a2 = bf2f(av.z), a3 = bf2f(av.w);
    float d0 = bf2f(dv.x), d1 = bf2f(dv.y), d2 = bf2f(dv.z), d3 = bf2f(dv.w);
    float p1 = a0 * w1.x + a1 * w1.y + a2 * w1.z + a3 * w1.w;
    float p2 = d0 * w2.x + d1 * w2.y + d2 * w2.z + d3 * w2.w;
    float p3 = d0 * w3.x + d1 * w3.y + d2 * w3.z + d3 * w3.w;
    float p4 = d0 * w4.x + d1 * w4.y + d2 * w4.z + d3 * w4.w;
#pragma unroll
    for (int off = 16; off >= 1; off >>= 1) {
        p1 += __shfl_down(p1, off, 32);
        p2 += __shfl_down(p2, off, 32);
        p3 += __shfl_down(p3, off, 32);
        p4 += __shfl_down(p4, off, 32);
    }
    if ((lane & 31) == 0) {
        int h = lane >> 5;
        as_ad[n * 2 + h] = p1;
        ad_ad[n * 2 + h] = p2;
        as_dd[n * 2 + h] = p3;
        ad_dd[n * 2 + h] = p4;
    }
}

// ---------------- 3a. degree histogram, both edge sets ------------------------------
__global__ __launch_bounds__(256) void count_edges2(const int* __restrict__ eiA, int* __restrict__ cntA,
                                                    const int* __restrict__ eiB, int* __restrict__ cntB, int E) {
    int idx = blockIdx.x * 256 + threadIdx.x;
    int which = idx >= E;
    int e = idx - (which ? E : 0);
    if (e >= E) return;
    const int* ei = which ? eiB : eiA;
    int* cnt = which ? cntB : cntA;
    atomicAdd(&cnt[ei[E + e]], 1);
}

// ---------------- 3b. exclusive scan of two count arrays ----------------------------
__global__ __launch_bounds__(1024) void scan_two(const int* __restrict__ cntA, int* __restrict__ offA,
                                                 const int* __restrict__ cntB, int* __restrict__ offB, int n) {
    const int* cnt = blockIdx.x ? cntB : cntA;
    int* off = blockIdx.x ? offB : offA;
    __shared__ int smem[1024];
    __shared__ int carry_s;
    int tid = threadIdx.x;
    if (tid == 0) carry_s = 0;
    __syncthreads();
    for (int base = 0; base < n; base += 1024) {
        int i = base + tid;
        int v = (i < n) ? cnt[i] : 0;
        smem[tid] = v;
        __syncthreads();
#pragma unroll
        for (int d = 1; d < 1024; d <<= 1) {
            int t = (tid >= d) ? smem[tid - d] : 0;
            __syncthreads();
            smem[tid] += t;
            __syncthreads();
        }
        int incl = smem[tid];
        int carry = carry_s;
        if (i < n) off[i] = carry + incl - v;   // exclusive
        __syncthreads();
        if (tid == 1023) carry_s = carry + smem[1023];
        __syncthreads();
    }
    if (tid == 0) off[n] = carry_s;
}

// ---------------- 3c. fill CSR src lists, both edge sets ----------------------------
__global__ __launch_bounds__(256) void fill_csr2(const int* __restrict__ eiA, const int* __restrict__ offA,
                                                 int* __restrict__ curA, int* __restrict__ srcsA,
                                                 const int* __restrict__ eiB, const int* __restrict__ offB,
                                                 int* __restrict__ curB, int* __restrict__ srcsB, int E) {
    int idx = blockIdx.x * 256 + threadIdx.x;
    int which = idx >= E;
    int e = idx - (which ? E : 0);
    if (e >= E) return;
    const int* ei = which ? eiB : eiA;
    const int* off = which ? offB : offA;
    int* cursor = which ? curB : curA;
    int* srcs = which ? srcsB : srcsA;
    int s = ei[e], d = ei[E + e];
    int slot = off[d] + atomicAdd(&cursor[d], 1);
    srcs[slot] = s;
}

// ---------------- 4. gather: one wave per dst node, both metapaths ------------------
__global__ __launch_bounds__(256) void edge_gather2(const int* __restrict__ offA, const int* __restrict__ srcsA,
                                                    const float* __restrict__ asA, const float* __restrict__ adA,
                                                    const u16* __restrict__ hA, float* __restrict__ outA,
                                                    const int* __restrict__ offB, const int* __restrict__ srcsB,
                                                    const float* __restrict__ asB, const float* __restrict__ adB,
                                                    const u16* __restrict__ hB, float* __restrict__ outB, int N) {
    int gid = blockIdx.x * 256 + threadIdx.x;
    int dall = gid >> 6;
    int which = dall >= N;
    int d = dall - (which ? N : 0);
    if (d >= N) return;
    const int* off = which ? offB : offA;
    const int* srcs = which ? srcsB : srcsA;
    const float* a_src = which ? asB : asA;
    const float* a_dst = which ? adB : adA;
    const u16* h = which ? hB : hA;
    float* out = which ? outB : outA;
    int lane = gid & 63;
    int hh = lane >> 5;
    int f = lane * 4;
    float ad0 = a_dst[d * 2 + hh];
    int beg = off[d], end = off[d + 1];
    float4 acc = {0.f, 0.f, 0.f, 0.f};
    float S = 0.f;
    for (int p = beg; p < end; ++p) {
        int s = srcs[p];
        float v = a_src[s * 2 + hh] + ad0;
        v = v > 0.f ? v : 0.2f * v;           // leaky_relu(0.2)
        float ex = __expf(v);
        S += ex;
        ushort4 xv = *(const ushort4*)(h + (size_t)s * 256 + f);
        acc.x += ex * bf2f(xv.x);
        acc.y += ex * bf2f(xv.y);
        acc.z += ex * bf2f(xv.z);
        acc.w += ex * bf2f(xv.w);
    }
    float inv = 1.f / (S + 1e-16f);
    float4 o = {acc.x * inv, acc.y * inv, acc.z * inv, acc.w * inv};
    *(float4*)(out + (size_t)d * 256 + f) = o;
}

// ---------------- 5. semantic scores, both metapaths in one dispatch ----------------
#define SK 264
__global__ __launch_bounds__(256) void kgemm_score2(const float* __restrict__ outA,
                                                    const float* __restrict__ outB,
                                                    const float* __restrict__ kW,
                                                    const float* __restrict__ kb,
                                                    const float* __restrict__ qv,
                                                    float* __restrict__ score) {
    __shared__ u16 Bs[128 * SK];          // 66 KB
    __shared__ float red[4];
    int slot = blockIdx.x >> 8;           // 0..1
    int b = blockIdx.x & 255;
    const float* outm = slot ? outB : outA;
    int bn = b & 1;
    int bidx = b >> 1;                    // 0..127
    int tid = threadIdx.x;
    int w = tid >> 6, lane = tid & 63;
    int row16 = lane & 15, quad = lane >> 4;

#pragma unroll
    for (int i = 0; i < 16; ++i) {
        int c = tid + 256 * i;
        int r = c >> 5, col8 = (c & 31) * 8;
        const float* src = kW + (size_t)(bn * 128 + r) * 256 + col8;
        *(bf16x8*)(Bs + r * SK + col8) = cvt8(*(const f32x4*)src, *(const f32x4*)(src + 4));
    }
    __syncthreads();

    float kb0 = kb[bn * 128 + w * 32 + row16];
    float qn0 = qv[bn * 128 + w * 32 + row16];
    float kb1 = kb[bn * 128 + w * 32 + 16 + row16];
    float qn1 = qv[bn * 128 + w * 32 + 16 + row16];
    const u16* b0 = Bs + (w * 32 + row16) * SK + quad * 8;
    const u16* b1 = Bs + (w * 32 + 16 + row16) * SK + quad * 8;

    float p = 0.f;
    for (int mt = bidx; mt < 1250; mt += 128) {
        const float* arow = outm + (size_t)(mt * 16 + row16) * 256 + quad * 8;
        f32x4 a0[8], a1[8];
#pragma unroll
        for (int s = 0; s < 8; ++s) {
            a0[s] = *(const f32x4*)(arow + s * 32);
            a1[s] = *(const f32x4*)(arow + s * 32 + 4);
        }
        f32x4 acc0 = {0.f,0.f,0.f,0.f}, acc1 = {0.f,0.f,0.f,0.f};
#pragma unroll
        for (int s = 0; s < 8; ++s) {
            f32x4 x0 = a0[s], x1 = a1[s];
#pragma unroll
            for (int j = 0; j < 4; ++j) {
                x0[j] = x0[j] > 0.f ? x0[j] : 0.f;
                x1[j] = x1[j] > 0.f ? x1[j] : 0.f;
            }
            bf16x8 af = cvt8(x0, x1);
            bf16x8 bf0 = *(const bf16x8*)(b0 + s * 32);
            bf16x8 bf1 = *(const bf16x8*)(b1 + s * 32);
            acc0 = __builtin_amdgcn_mfma_f32_16x16x32_bf16(af, bf0, acc0, 0, 0, 0);
            acc1 = __builtin_amdgcn_mfma_f32_16x16x32_bf16(af, bf1, acc1, 0, 0, 0);
        }
#pragma unroll
        for (int r = 0; r < 4; ++r) {
            p += qn0 * fast_tanh(acc0[r] + kb0);
            p += qn1 * fast_tanh(acc1[r] + kb1);
        }
    }
#pragma unroll
    for (int off = 32; off >= 1; off >>= 1) p += __shfl_down(p, off, 64);
    if (lane == 0) red[w] = p;
    __syncthreads();
    if (tid == 0) unsafeAtomicAdd(&score[slot], red[0] + red[1] + red[2] + red[3]);
}

// ---------------- 6. softmax over 2 metapath scores, blend, gather del_idx ----------
__global__ __launch_bounds__(256) void final_combine(const float* __restrict__ out_ad,
                                                     const float* __restrict__ out_dd,
                                                     const float* __restrict__ score,
                                                     const int* __restrict__ del_idx,
                                                     float* __restrict__ out) {
    int i = blockIdx.x;
    int f = threadIdx.x;
    int node = del_idx[i];
    float s0 = score[0] * (1.f / 20000.f);
    float s1 = score[1] * (1.f / 20000.f);
    float m = fmaxf(s0, s1);
    float e0 = __expf(s0 - m), e1 = __expf(s1 - m);
    float inv = 1.f / (e0 + e1);
    float a0 = e0 * inv, a1 = e1 * inv;
    float v0 = out_ad[(size_t)node * 256 + f]; v0 = v0 > 0.f ? v0 : 0.f;
    float v1 = out_dd[(size_t)node * 256 + f]; v1 = v1 > 0.f ? v1 : 0.f;
    out[(size_t)i * 256 + f] = a0 * v0 + a1 * v1;
}

extern "C" void kernel_launch(void* const* d_in, const int* in_sizes, int n_in,
                              void* d_out, int out_size, void* d_ws, size_t ws_size,
                              hipStream_t stream) {
    const float* x_add    = (const float*)d_in[0];
    const float* x_del    = (const float*)d_in[1];
    const float* W_add    = (const float*)d_in[2];
    const float* b_add    = (const float*)d_in[3];
    const float* W_del    = (const float*)d_in[4];
    const float* b_del    = (const float*)d_in[5];
    const float* att_ad_s = (const float*)d_in[6];
    const float* att_ad_d = (const float*)d_in[7];
    const float* att_dd_s = (const float*)d_in[12];
    const float* att_dd_d = (const float*)d_in[13];
    const float* k_W      = (const float*)d_in[14];
    const float* k_b      = (const float*)d_in[15];
    const float* q        = (const float*)d_in[16];
    const int* ei_ad      = (const int*)d_in[17];
    const int* ei_dd      = (const int*)d_in[20];
    const int* del_idx    = (const int*)d_in[21];
    float* out = (float*)d_out;

    const int N = 20000, E = 200000;
    char* ws = (char*)d_ws;
    size_t o = 0;
    // ---- zeroed region ----
    int* cnt_ad = (int*)(ws + o); o += (size_t)N * 4;
    int* cur_ad = (int*)(ws + o); o += (size_t)N * 4;
    int* cnt_dd = (int*)(ws + o); o += (size_t)N * 4;
    int* cur_dd = (int*)(ws + o); o += (size_t)N * 4;
    float* score = (float*)(ws + o); o += 256;
    size_t zero_bytes = o;
    // ---- written-once region ----
    int* off_ad = (int*)(ws + o); o += (size_t)(N + 1) * 4;
    int* off_dd = (int*)(ws + o); o += (size_t)(N + 1) * 4;
    int* srcs_ad = (int*)(ws + o); o += (size_t)E * 4;
    int* srcs_dd = (int*)(ws + o); o += (size_t)E * 4;
    float* out_ad = (float*)(ws + o); o += (size_t)N * 256 * 4;
    float* out_dd = (float*)(ws + o); o += (size_t)N * 256 * 4;
    u16* ha    = (u16*)(ws + o); o += (size_t)N * 256 * 2;
    u16* hd    = (u16*)(ws + o); o += (size_t)N * 256 * 2;
    float* as_ad = (float*)(ws + o); o += (size_t)N * 2 * 4;
    float* ad_ad = (float*)(ws + o); o += (size_t)N * 2 * 4;
    float* as_dd = (float*)(ws + o); o += (size_t)N * 2 * 4;
    float* ad_dd = (float*)(ws + o); o += (size_t)N * 2 * 4;

    hipMemsetAsync(d_ws, 0, zero_bytes, stream);

    // CSR build (fused pairs)
    count_edges2<<<(2 * E + 255) / 256, 256, 0, stream>>>(ei_ad, cnt_ad, ei_dd, cnt_dd, E);
    scan_two<<<2, 1024, 0, stream>>>(cnt_ad, off_ad, cnt_dd, off_dd, N);
    fill_csr2<<<(2 * E + 255) / 256, 256, 0, stream>>>(ei_ad, off_ad, cur_ad, srcs_ad,
                                                       ei_dd, off_dd, cur_dd, srcs_dd, E);

    // both projections: barrier-free persistent-B, exactly 256 blocks (1/CU)
    gemm_persist<<<256, 256, 0, stream>>>(x_add, W_add, b_add, ha,
                                          x_del, W_del, b_del, hd);
    node_scores<<<5000, 256, 0, stream>>>(ha, hd, att_ad_s, att_ad_d, att_dd_s, att_dd_d,
                                          as_ad, ad_ad, as_dd, ad_dd, N);

    edge_gather2<<<10000, 256, 0, stream>>>(off_ad, srcs_ad, as_ad, ad_ad, ha, out_ad,
                                            off_dd, srcs_dd, as_dd, ad_dd, hd, out_dd, N);

    kgemm_score2<<<512, 256, 0, stream>>>(out_ad, out_dd, k_W, k_b, q, score);
    final_combine<<<4096, 256, 0, stream>>>(out_ad, out_dd, score, del_idx, out);
}

// Round 8
// 380.416 us; speedup vs baseline: 1.3035x; 1.3035x over previous
//
#include <hip/hip_runtime.h>
#include <hip/hip_bf16.h>

// HAN forward, del-branch only (add-branch _group output is unused in the reference).
// Inputs f32 / int32; output f32 [4096,256]. h and out_* stored bf16.
//
// R8 changes (R7 persistent-B regressed: 1 wave/SIMD, no latency hiding — reverted):
//  - gemm_h2: R6 tile (BM=BN=128, BK=32) + LDS DOUBLE-BUFFER, one barrier/k-step.
//    Prefetch next k-tile into f32 regs while MFMAs consume current LDS buffer;
//    cvt+LDS-write after compute (hides global latency under 16 MFMAs).
//  - out_ad/out_dd bf16: halves edge_gather write + kgemm_score read traffic
//    (relu commutes with bf16 rounding).
//  - scan_two: shuffle-based (3 barriers/chunk vs ~20 + 10x1024 smem adds).

typedef unsigned short u16;
typedef __attribute__((ext_vector_type(8))) __bf16 bf16x8;
typedef __attribute__((ext_vector_type(4))) float f32x4;

__device__ inline float bf2f(u16 u) {
    union { unsigned int i; float f; } c; c.i = ((unsigned int)u) << 16; return c.f;
}
__device__ inline u16 f2bf(float f) {  // round-to-nearest-even
    union { float f; unsigned int i; } c; c.f = f;
    return (u16)((c.i + 0x7fffu + ((c.i >> 16) & 1u)) >> 16);
}
__device__ inline bf16x8 cvt8(f32x4 a, f32x4 b) {
    bf16x8 r;
    r[0] = (__bf16)a[0]; r[1] = (__bf16)a[1]; r[2] = (__bf16)a[2]; r[3] = (__bf16)a[3];
    r[4] = (__bf16)b[0]; r[5] = (__bf16)b[1]; r[6] = (__bf16)b[2]; r[7] = (__bf16)b[3];
    return r;
}
__device__ inline float fast_tanh(float x) {
    x = fminf(9.f, fmaxf(-9.f, x));
    float t = __expf(2.f * x);
    return (t - 1.f) / (t + 1.f);
}

// ---------------- 1. h = X @ W^T + b, both node types, LDS double-buffered ----------
#define SA 40
#define MTILES 157                       // ceil(20000/128)
__global__ __launch_bounds__(256) void gemm_h2(const float* __restrict__ X0, const float* __restrict__ W0,
                                               const float* __restrict__ b0, u16* __restrict__ H0,
                                               const float* __restrict__ X1, const float* __restrict__ W1,
                                               const float* __restrict__ b1, u16* __restrict__ H1, int M) {
    __shared__ u16 As[2][128 * SA];      // 2 x 10 KB
    __shared__ u16 Bs[2][128 * SA];
    int id = blockIdx.x;
    int which = id >= MTILES * 2;
    if (which) id -= MTILES * 2;
    int bm = id >> 1, bn = id & 1;
    const float* X = which ? X1 : X0;
    const float* W = which ? W1 : W0;
    const float* bias = which ? b1 : b0;
    u16* H = which ? H1 : H0;

    int tid = threadIdx.x;
    int w = tid >> 6, lane = tid & 63;
    int wm = w & 1, wn = w >> 1;
    int row16 = lane & 15, quad = lane >> 4;

    // staging: 512 chunks of 8 f32 per tile; thread handles chunks tid and tid+256
    int r0 = tid >> 2, r1 = (tid + 256) >> 2, cc = (tid & 3) * 8;
    int ar0 = bm * 128 + r0; if (ar0 > M - 1) ar0 = M - 1;
    int ar1 = bm * 128 + r1; if (ar1 > M - 1) ar1 = M - 1;
    const float* ag0 = X + (size_t)ar0 * 768 + cc;
    const float* ag1 = X + (size_t)ar1 * 768 + cc;
    const float* bg0 = W + (size_t)(bn * 128 + r0) * 768 + cc;
    const float* bg1 = W + (size_t)(bn * 128 + r1) * 768 + cc;
    int aoff0 = r0 * SA + cc, aoff1 = r1 * SA + cc;

    int ardo = (wm * 64 + row16) * SA + quad * 8;
    int brdo = (wn * 64 + row16) * SA + quad * 8;

    f32x4 ra[4], rb[4];
    // prologue: tile 0 -> buf 0
    ra[0] = *(const f32x4*)(ag0);     ra[1] = *(const f32x4*)(ag0 + 4);
    ra[2] = *(const f32x4*)(ag1);     ra[3] = *(const f32x4*)(ag1 + 4);
    rb[0] = *(const f32x4*)(bg0);     rb[1] = *(const f32x4*)(bg0 + 4);
    rb[2] = *(const f32x4*)(bg1);     rb[3] = *(const f32x4*)(bg1 + 4);
    *(bf16x8*)(As[0] + aoff0) = cvt8(ra[0], ra[1]);
    *(bf16x8*)(As[0] + aoff1) = cvt8(ra[2], ra[3]);
    *(bf16x8*)(Bs[0] + aoff0) = cvt8(rb[0], rb[1]);
    *(bf16x8*)(Bs[0] + aoff1) = cvt8(rb[2], rb[3]);
    __syncthreads();

    f32x4 acc[4][4] = {};
#pragma unroll
    for (int ks = 0; ks < 24; ++ks) {
        int cur = ks & 1;
        if (ks < 23) {                   // prefetch tile ks+1 into regs
            int k = (ks + 1) * 32;
            ra[0] = *(const f32x4*)(ag0 + k); ra[1] = *(const f32x4*)(ag0 + k + 4);
            ra[2] = *(const f32x4*)(ag1 + k); ra[3] = *(const f32x4*)(ag1 + k + 4);
            rb[0] = *(const f32x4*)(bg0 + k); rb[1] = *(const f32x4*)(bg0 + k + 4);
            rb[2] = *(const f32x4*)(bg1 + k); rb[3] = *(const f32x4*)(bg1 + k + 4);
        }
        bf16x8 af[4], bv[4];
#pragma unroll
        for (int i = 0; i < 4; ++i) {
            af[i] = *(const bf16x8*)(As[cur] + ardo + i * 16 * SA);
            bv[i] = *(const bf16x8*)(Bs[cur] + brdo + i * 16 * SA);
        }
#pragma unroll
        for (int mi = 0; mi < 4; ++mi)
#pragma unroll
            for (int ni = 0; ni < 4; ++ni)
                acc[mi][ni] = __builtin_amdgcn_mfma_f32_16x16x32_bf16(af[mi], bv[ni], acc[mi][ni], 0, 0, 0);
        if (ks < 23) {                   // write prefetched tile to other buffer
            int nxt = cur ^ 1;
            *(bf16x8*)(As[nxt] + aoff0) = cvt8(ra[0], ra[1]);
            *(bf16x8*)(As[nxt] + aoff1) = cvt8(ra[2], ra[3]);
            *(bf16x8*)(Bs[nxt] + aoff0) = cvt8(rb[0], rb[1]);
            *(bf16x8*)(Bs[nxt] + aoff1) = cvt8(rb[2], rb[3]);
            __syncthreads();             // the ONLY barrier per k-step
        }
    }
#pragma unroll
    for (int ni = 0; ni < 4; ++ni) {
        int gcol = bn * 128 + wn * 64 + ni * 16 + row16;
        float bvv = bias[gcol];
#pragma unroll
        for (int mi = 0; mi < 4; ++mi) {
#pragma unroll
            for (int r = 0; r < 4; ++r) {
                int grow = bm * 128 + wm * 64 + mi * 16 + quad * 4 + r;
                if (grow < M) H[(size_t)grow * 256 + gcol] = f2bf(acc[mi][ni][r] + bvv);
            }
        }
    }
}

// ---------------- 2. per-(node,head) attention scores (h bf16) ----------------------
__global__ __launch_bounds__(256) void node_scores(const u16* __restrict__ ha, const u16* __restrict__ hd,
                                                   const float* __restrict__ w_ads, const float* __restrict__ w_add,
                                                   const float* __restrict__ w_dds, const float* __restrict__ w_ddd,
                                                   float* __restrict__ as_ad, float* __restrict__ ad_ad,
                                                   float* __restrict__ as_dd, float* __restrict__ ad_dd, int N) {
    int gid = blockIdx.x * 256 + threadIdx.x;
    int n = gid >> 6;
    if (n >= N) return;
    int lane = gid & 63;
    int f = lane * 4;
    ushort4 av = *(const ushort4*)(ha + (size_t)n * 256 + f);
    ushort4 dv = *(const ushort4*)(hd + (size_t)n * 256 + f);
    float4 w1 = *(const float4*)(w_ads + f);
    float4 w2 = *(const float4*)(w_add + f);
    float4 w3 = *(const float4*)(w_dds + f);
    float4 w4 = *(const float4*)(w_ddd + f);
    float a0 = bf2f(av.x), a1 = bf2f(av.y), a2 = bf2f(av.z), a3 = bf2f(av.w);
    float d0 = bf2f(dv.x), d1 = bf2f(dv.y), d2 = bf2f(dv.z), d3 = bf2f(dv.w);
    float p1 = a0 * w1.x + a1 * w1.y + a2 * w1.z + a3 * w1.w;
    float p2 = d0 * w2.x + d1 * w2.y + d2 * w2.z + d3 * w2.w;
    float p3 = d0 * w3.x + d1 * w3.y + d2 * w3.z + d3 * w3.w;
    float p4 = d0 * w4.x + d1 * w4.y + d2 * w4.z + d3 * w4.w;
#pragma unroll
    for (int off = 16; off >= 1; off >>= 1) {
        p1 += __shfl_down(p1, off, 32);
        p2 += __shfl_down(p2, off, 32);
        p3 += __shfl_down(p3, off, 32);
        p4 += __shfl_down(p4, off, 32);
    }
    if ((lane & 31) == 0) {
        int h = lane >> 5;
        as_ad[n * 2 + h] = p1;
        ad_ad[n * 2 + h] = p2;
        as_dd[n * 2 + h] = p3;
        ad_dd[n * 2 + h] = p4;
    }
}

// ---------------- 3a. degree histogram, both edge sets ------------------------------
__global__ __launch_bounds__(256) void count_edges2(const int* __restrict__ eiA, int* __restrict__ cntA,
                                                    const int* __restrict__ eiB, int* __restrict__ cntB, int E) {
    int idx = blockIdx.x * 256 + threadIdx.x;
    int which = idx >= E;
    int e = idx - (which ? E : 0);
    if (e >= E) return;
    const int* ei = which ? eiB : eiA;
    int* cnt = which ? cntB : cntA;
    atomicAdd(&cnt[ei[E + e]], 1);
}

// ---------------- 3b. exclusive scan (shuffle-based, 3 barriers/chunk) --------------
__global__ __launch_bounds__(1024) void scan_two(const int* __restrict__ cntA, int* __restrict__ offA,
                                                 const int* __restrict__ cntB, int* __restrict__ offB, int n) {
    const int* cnt = blockIdx.x ? cntB : cntA;
    int* off = blockIdx.x ? offB : offA;
    __shared__ int wsum[16];
    __shared__ int woff[16];
    __shared__ int tot_s;
    __shared__ int carry_s;
    int tid = threadIdx.x, wid = tid >> 6, lane = tid & 63;
    if (tid == 0) carry_s = 0;
    __syncthreads();
    for (int base = 0; base < n; base += 1024) {
        int i = base + tid;
        int v = (i < n) ? cnt[i] : 0;
        int x = v;
#pragma unroll
        for (int d = 1; d < 64; d <<= 1) {     // inclusive wave scan
            int t = __shfl_up(x, d, 64);
            if (lane >= d) x += t;
        }
        if (lane == 63) wsum[wid] = x;
        __syncthreads();
        if (wid == 0) {
            int s = (lane < 16) ? wsum[lane] : 0;
#pragma unroll
            for (int d = 1; d < 16; d <<= 1) {
                int t = __shfl_up(s, d, 64);
                if (lane >= d) s += t;
            }
            if (lane < 16) woff[lane] = s - wsum[lane];   // exclusive wave offsets
            if (lane == 15) tot_s = s;
        }
        __syncthreads();
        int carry = carry_s;
        if (i < n) off[i] = carry + woff[wid] + x - v;    // exclusive
        __syncthreads();
        if (tid == 0) carry_s = carry + tot_s;
    }
    __syncthreads();
    if (tid == 0) off[n] = carry_s;
}

// ---------------- 3c. fill CSR src lists, both edge sets ----------------------------
__global__ __launch_bounds__(256) void fill_csr2(const int* __restrict__ eiA, const int* __restrict__ offA,
                                                 int* __restrict__ curA, int* __restrict__ srcsA,
                                                 const int* __restrict__ eiB, const int* __restrict__ offB,
                                                 int* __restrict__ curB, int* __restrict__ srcsB, int E) {
    int idx = blockIdx.x * 256 + threadIdx.x;
    int which = idx >= E;
    int e = idx - (which ? E : 0);
    if (e >= E) return;
    const int* ei = which ? eiB : eiA;
    const int* off = which ? offB : offA;
    int* cursor = which ? curB : curA;
    int* srcs = which ? srcsB : srcsA;
    int s = ei[e], d = ei[E + e];
    int slot = off[d] + atomicAdd(&cursor[d], 1);
    srcs[slot] = s;
}

// ---------------- 4. gather: one wave per dst node; out bf16 ------------------------
__global__ __launch_bounds__(256) void edge_gather2(const int* __restrict__ offA, const int* __restrict__ srcsA,
                                                    const float* __restrict__ asA, const float* __restrict__ adA,
                                                    const u16* __restrict__ hA, u16* __restrict__ outA,
                                                    const int* __restrict__ offB, const int* __restrict__ srcsB,
                                                    const float* __restrict__ asB, const float* __restrict__ adB,
                                                    const u16* __restrict__ hB, u16* __restrict__ outB, int N) {
    int gid = blockIdx.x * 256 + threadIdx.x;
    int dall = gid >> 6;
    int which = dall >= N;
    int d = dall - (which ? N : 0);
    if (d >= N) return;
    const int* off = which ? offB : offA;
    const int* srcs = which ? srcsB : srcsA;
    const float* a_src = which ? asB : asA;
    const float* a_dst = which ? adB : adA;
    const u16* h = which ? hB : hA;
    u16* out = which ? outB : outA;
    int lane = gid & 63;
    int hh = lane >> 5;
    int f = lane * 4;
    float ad0 = a_dst[d * 2 + hh];
    int beg = off[d], end = off[d + 1];
    float4 acc = {0.f, 0.f, 0.f, 0.f};
    float S = 0.f;
    for (int p = beg; p < end; ++p) {
        int s = srcs[p];
        float v = a_src[s * 2 + hh] + ad0;
        v = v > 0.f ? v : 0.2f * v;           // leaky_relu(0.2)
        float ex = __expf(v);
        S += ex;
        ushort4 xv = *(const ushort4*)(h + (size_t)s * 256 + f);
        acc.x += ex * bf2f(xv.x);
        acc.y += ex * bf2f(xv.y);
        acc.z += ex * bf2f(xv.z);
        acc.w += ex * bf2f(xv.w);
    }
    float inv = 1.f / (S + 1e-16f);
    ushort4 o = {f2bf(acc.x * inv), f2bf(acc.y * inv), f2bf(acc.z * inv), f2bf(acc.w * inv)};
    *(ushort4*)(out + (size_t)d * 256 + f) = o;
}

// ---------------- 5. semantic scores, both metapaths; A is bf16 ---------------------
// relu on bf16 == bf16-round of relu(f32): sign-bit test -> zero.
#define SK 264
__global__ __launch_bounds__(256) void kgemm_score2(const u16* __restrict__ outA,
                                                    const u16* __restrict__ outB,
                                                    const float* __restrict__ kW,
                                                    const float* __restrict__ kb,
                                                    const float* __restrict__ qv,
                                                    float* __restrict__ score) {
    __shared__ u16 Bs[128 * SK];          // 66 KB
    __shared__ float red[4];
    int slot = blockIdx.x >> 8;           // 0..1
    int b = blockIdx.x & 255;
    const u16* outm = slot ? outB : outA;
    int bn = b & 1;
    int bidx = b >> 1;                    // 0..127
    int tid = threadIdx.x;
    int w = tid >> 6, lane = tid & 63;
    int row16 = lane & 15, quad = lane >> 4;

#pragma unroll
    for (int i = 0; i < 16; ++i) {
        int c = tid + 256 * i;
        int r = c >> 5, col8 = (c & 31) * 8;
        const float* src = kW + (size_t)(bn * 128 + r) * 256 + col8;
        *(bf16x8*)(Bs + r * SK + col8) = cvt8(*(const f32x4*)src, *(const f32x4*)(src + 4));
    }
    __syncthreads();

    float kb0 = kb[bn * 128 + w * 32 + row16];
    float qn0 = qv[bn * 128 + w * 32 + row16];
    float kb1 = kb[bn * 128 + w * 32 + 16 + row16];
    float qn1 = qv[bn * 128 + w * 32 + 16 + row16];
    const u16* b0 = Bs + (w * 32 + row16) * SK + quad * 8;
    const u16* b1 = Bs + (w * 32 + 16 + row16) * SK + quad * 8;

    union U { uint4 q; u16 s[8]; bf16x8 v; };
    float p = 0.f;
    for (int mt = bidx; mt < 1250; mt += 128) {
        const u16* arow = outm + (size_t)(mt * 16 + row16) * 256 + quad * 8;
        U a[8];
#pragma unroll
        for (int s8 = 0; s8 < 8; ++s8) a[s8].q = *(const uint4*)(arow + s8 * 32);
        f32x4 acc0 = {0.f,0.f,0.f,0.f}, acc1 = {0.f,0.f,0.f,0.f};
#pragma unroll
        for (int s8 = 0; s8 < 8; ++s8) {
#pragma unroll
            for (int j = 0; j < 8; ++j)       // relu in bf16 domain
                if (a[s8].s[j] & 0x8000u) a[s8].s[j] = 0;
            bf16x8 bf0 = *(const bf16x8*)(b0 + s8 * 32);
            bf16x8 bf1 = *(const bf16x8*)(b1 + s8 * 32);
            acc0 = __builtin_amdgcn_mfma_f32_16x16x32_bf16(a[s8].v, bf0, acc0, 0, 0, 0);
            acc1 = __builtin_amdgcn_mfma_f32_16x16x32_bf16(a[s8].v, bf1, acc1, 0, 0, 0);
        }
#pragma unroll
        for (int r = 0; r < 4; ++r) {
            p += qn0 * fast_tanh(acc0[r] + kb0);
            p += qn1 * fast_tanh(acc1[r] + kb1);
        }
    }
#pragma unroll
    for (int off = 32; off >= 1; off >>= 1) p += __shfl_down(p, off, 64);
    if (lane == 0) red[w] = p;
    __syncthreads();
    if (tid == 0) unsafeAtomicAdd(&score[slot], red[0] + red[1] + red[2] + red[3]);
}

// ---------------- 6. softmax over 2 metapath scores, blend, gather del_idx ----------
__global__ __launch_bounds__(256) void final_combine(const u16* __restrict__ out_ad,
                                                     const u16* __restrict__ out_dd,
                                                     const float* __restrict__ score,
                                                     const int* __restrict__ del_idx,
                                                     float* __restrict__ out) {
    int i = blockIdx.x;
    int f = threadIdx.x;
    int node = del_idx[i];
    float s0 = score[0] * (1.f / 20000.f);
    float s1 = score[1] * (1.f / 20000.f);
    float m = fmaxf(s0, s1);
    float e0 = __expf(s0 - m), e1 = __expf(s1 - m);
    float inv = 1.f / (e0 + e1);
    float a0 = e0 * inv, a1 = e1 * inv;
    float v0 = bf2f(out_ad[(size_t)node * 256 + f]); v0 = v0 > 0.f ? v0 : 0.f;
    float v1 = bf2f(out_dd[(size_t)node * 256 + f]); v1 = v1 > 0.f ? v1 : 0.f;
    out[(size_t)i * 256 + f] = a0 * v0 + a1 * v1;
}

extern "C" void kernel_launch(void* const* d_in, const int* in_sizes, int n_in,
                              void* d_out, int out_size, void* d_ws, size_t ws_size,
                              hipStream_t stream) {
    const float* x_add    = (const float*)d_in[0];
    const float* x_del    = (const float*)d_in[1];
    const float* W_add    = (const float*)d_in[2];
    const float* b_add    = (const float*)d_in[3];
    const float* W_del    = (const float*)d_in[4];
    const float* b_del    = (const float*)d_in[5];
    const float* att_ad_s = (const float*)d_in[6];
    const float* att_ad_d = (const float*)d_in[7];
    const float* att_dd_s = (const float*)d_in[12];
    const float* att_dd_d = (const float*)d_in[13];
    const float* k_W      = (const float*)d_in[14];
    const float* k_b      = (const float*)d_in[15];
    const float* q        = (const float*)d_in[16];
    const int* ei_ad      = (const int*)d_in[17];
    const int* ei_dd      = (const int*)d_in[20];
    const int* del_idx    = (const int*)d_in[21];
    float* out = (float*)d_out;

    const int N = 20000, E = 200000;
    char* ws = (char*)d_ws;
    size_t o = 0;
    // ---- zeroed region ----
    int* cnt_ad = (int*)(ws + o); o += (size_t)N * 4;
    int* cur_ad = (int*)(ws + o); o += (size_t)N * 4;
    int* cnt_dd = (int*)(ws + o); o += (size_t)N * 4;
    int* cur_dd = (int*)(ws + o); o += (size_t)N * 4;
    float* score = (float*)(ws + o); o += 256;
    size_t zero_bytes = o;
    // ---- written-once region ----
    int* off_ad = (int*)(ws + o); o += (size_t)(N + 1) * 4;
    int* off_dd = (int*)(ws + o); o += (size_t)(N + 1) * 4;
    int* srcs_ad = (int*)(ws + o); o += (size_t)E * 4;
    int* srcs_dd = (int*)(ws + o); o += (size_t)E * 4;
    u16* out_ad = (u16*)(ws + o); o += (size_t)N * 256 * 2;
    u16* out_dd = (u16*)(ws + o); o += (size_t)N * 256 * 2;
    u16* ha    = (u16*)(ws + o); o += (size_t)N * 256 * 2;
    u16* hd    = (u16*)(ws + o); o += (size_t)N * 256 * 2;
    float* as_ad = (float*)(ws + o); o += (size_t)N * 2 * 4;
    float* ad_ad = (float*)(ws + o); o += (size_t)N * 2 * 4;
    float* as_dd = (float*)(ws + o); o += (size_t)N * 2 * 4;
    float* ad_dd = (float*)(ws + o); o += (size_t)N * 2 * 4;

    hipMemsetAsync(d_ws, 0, zero_bytes, stream);

    // CSR build (fused pairs)
    count_edges2<<<(2 * E + 255) / 256, 256, 0, stream>>>(ei_ad, cnt_ad, ei_dd, cnt_dd, E);
    scan_two<<<2, 1024, 0, stream>>>(cnt_ad, off_ad, cnt_dd, off_dd, N);
    fill_csr2<<<(2 * E + 255) / 256, 256, 0, stream>>>(ei_ad, off_ad, cur_ad, srcs_ad,
                                                       ei_dd, off_dd, cur_dd, srcs_dd, E);

    // both projections in one dispatch: 2 * (157 m-tiles * 2 n-tiles) = 628 blocks
    gemm_h2<<<4 * MTILES, 256, 0, stream>>>(x_add, W_add, b_add, ha,
                                            x_del, W_del, b_del, hd, N);
    node_scores<<<5000, 256, 0, stream>>>(ha, hd, att_ad_s, att_ad_d, att_dd_s, att_dd_d,
                                          as_ad, ad_ad, as_dd, ad_dd, N);

    edge_gather2<<<10000, 256, 0, stream>>>(off_ad, srcs_ad, as_ad, ad_ad, ha, out_ad,
                                            off_dd, srcs_dd, as_dd, ad_dd, hd, out_dd, N);

    kgemm_score2<<<512, 256, 0, stream>>>(out_ad, out_dd, k_W, k_b, q, score);
    final_combine<<<4096, 256, 0, stream>>>(out_ad, out_dd, score, del_idx, out);
}